// Round 1
// baseline (137.161 us; speedup 1.0000x reference)
//
#include <hip/hip_runtime.h>
#include <math.h>

// ClownSelector R10: same per-wave tile as R7/R9, but 8-way K-split for TLP.
//
// R9 post-mortem: router_dots = 55us with VALUBusy 29%, Occupancy 17%,
// HBM 9% -> latency-bound, not efficiency-bound. Grid was 512 blocks x 4
// waves = 2 blocks/CU = 8 waves/CU; 2 waves/SIMD cannot hide the ds_read /
// proto-load latency in the k-loop. Instruction model: ~20M wave-instrs
// -> 16us @100% VALU issue; 29% busy predicts 56us (matches measurement).
//
// R10: 512-thread blocks (8 waves), each wave owns a 128-wide k-slice of the
// same 32-token x 64-expert tile. Per-lane inner loop is bit-identical to R9
// (32 fmac : ~6 overhead, depth-4 proto rotation, x chunk double-buffer,
// ZERO barriers in the K-loop). 16 waves/CU target. Reduction tree gains one
// level (8->4->2->1), two LDS buffers, deterministic order.
// LDS: xt 36KB + B0/B1 17.4KB + nq 1KB = 55.3KB -> 2 blocks/CU (110KB/160KB).
// __launch_bounds__(512,2): loose VGPR cap (R8 lesson: tight cap -> spills).

#define BB 8
#define SS 2048
#define DD 1024
#define EE 64
#define EPSV 1e-8f

#define FMA4(A, s, P) \
  A.x += (s) * (P).x; A.y += (s) * (P).y; A.z += (s) * (P).z; A.w += (s) * (P).w;

#define SUMSQ4(v) ((v).x * (v).x + (v).y * (v).y + (v).z * (v).z + (v).w * (v).w)

// ---- K0: proto[e][d] -> ptt[d][e] -----------------------------------------
__global__ __launch_bounds__(256) void repack_proto(
    const float* __restrict__ proto, float* __restrict__ ptt) {
  const int gid = blockIdx.x * 256 + threadIdx.x;  // 0..65535
  const int d = gid >> 6;
  const int e = gid & 63;
  ptt[gid] = proto[(size_t)e * DD + d];
}

// ---- K1: normalized per-row dots ------------------------------------------
__global__ __launch_bounds__(512, 2) void router_dots(
    const float* __restrict__ x, const float* __restrict__ ptt,
    float* __restrict__ dots) {
  __shared__ float xt[8][2][16][36];  // per-wave double-buffered x chunk
  __shared__ float B0[32][68];        // reduction buffers
  __shared__ float B1[32][68];
  __shared__ float nq[8][32];         // per-wave per-token sumsq partials

  const int lane = threadIdx.x & 63;
  const int w    = __builtin_amdgcn_readfirstlane(threadIdx.x >> 6);  // 0..7
  const int b    = blockIdx.x >> 6;          // 64 blocks per batch
  const int s0   = (blockIdx.x & 63) * 32;   // 32 tokens per block

  const int toks = lane & 31;  // staging: token
  const int kh   = lane >> 5;  // staging: k-half (8 floats)
  const int eg   = lane & 7;   // tile: expert group (8 e)
  const int tg   = lane >> 3;  // tile: token group (4 t)

  const float* xb = x + ((size_t)b * SS + s0) * DD;
  const int kbase = w * 128;   // this wave's k-slice (128 wide)

  float4 acc0[4], acc1[4];
#pragma unroll
  for (int i = 0; i < 4; ++i) {
    acc0[i] = make_float4(0.f, 0.f, 0.f, 0.f);
    acc1[i] = make_float4(0.f, 0.f, 0.f, 0.f);
  }
  float q = 0.0f;

  // ---- preload + stage chunk 0 into buf 0 ----
  {
    const float* xs = xb + (size_t)toks * DD + kbase + kh * 8;
    const float4 va = *(const float4*)(xs);
    const float4 vb = *(const float4*)(xs + 4);
    q += SUMSQ4(va) + SUMSQ4(vb);
    float* dstc = &xt[w][0][0][toks];
    dstc[(kh * 8 + 0) * 36] = va.x;
    dstc[(kh * 8 + 1) * 36] = va.y;
    dstc[(kh * 8 + 2) * 36] = va.z;
    dstc[(kh * 8 + 3) * 36] = va.w;
    dstc[(kh * 8 + 4) * 36] = vb.x;
    dstc[(kh * 8 + 5) * 36] = vb.y;
    dstc[(kh * 8 + 6) * 36] = vb.z;
    dstc[(kh * 8 + 7) * 36] = vb.w;
  }

  // ---- proto rotation preload: k = kbase..kbase+3 ----
  float4 pp0[4], pp1[4];
#pragma unroll
  for (int r = 0; r < 4; ++r) {
    const float* pr = ptt + (size_t)(kbase + r) * EE + eg * 8;
    pp0[r] = *(const float4*)(pr);
    pp1[r] = *(const float4*)(pr + 4);
  }

  for (int c = 0; c < 8; ++c) {   // 8 chunks x 16 k = 128 k
    const int cur = c & 1;
    // ---- prefetch next chunk's x (consumed after the k-loop) ----
    float4 na, nb;
    if (c + 1 < 8) {
      const float* xs = xb + (size_t)toks * DD + kbase + (c + 1) * 16 + kh * 8;
      na = *(const float4*)(xs);
      nb = *(const float4*)(xs + 4);
    }
    // ---- 16 k-steps: ds_read x-frag + rotated proto + 32 fmac ----
#pragma unroll
    for (int kk = 0; kk < 16; ++kk) {
      const int slot = kk & 3;
      const float4 xf = *(const float4*)(&xt[w][cur][kk][tg * 4]);
      const float4 p0 = pp0[slot];
      const float4 p1 = pp1[slot];
      int kpre = kbase + c * 16 + kk + 4;            // continuous rotation
      if (kpre > kbase + 127) kpre = kbase + 127;    // slice-tail clamp
      const float* pr = ptt + (size_t)kpre * EE + eg * 8;
      pp0[slot] = *(const float4*)(pr);
      pp1[slot] = *(const float4*)(pr + 4);
      FMA4(acc0[0], xf.x, p0) FMA4(acc1[0], xf.x, p1)
      FMA4(acc0[1], xf.y, p0) FMA4(acc1[1], xf.y, p1)
      FMA4(acc0[2], xf.z, p0) FMA4(acc1[2], xf.z, p1)
      FMA4(acc0[3], xf.w, p0) FMA4(acc1[3], xf.w, p1)
    }
    // ---- stage prefetched chunk into the other buffer ----
    if (c + 1 < 8) {
      q += SUMSQ4(na) + SUMSQ4(nb);
      float* dstc = &xt[w][cur ^ 1][0][toks];
      dstc[(kh * 8 + 0) * 36] = na.x;
      dstc[(kh * 8 + 1) * 36] = na.y;
      dstc[(kh * 8 + 2) * 36] = na.z;
      dstc[(kh * 8 + 3) * 36] = na.w;
      dstc[(kh * 8 + 4) * 36] = nb.x;
      dstc[(kh * 8 + 5) * 36] = nb.y;
      dstc[(kh * 8 + 6) * 36] = nb.z;
      dstc[(kh * 8 + 7) * 36] = nb.w;
    }
  }

  // sumsq: combine the two k-halves of each token; kh==0 lanes publish
  q += __shfl_xor(q, 32);
  if (kh == 0) nq[w][toks] = q;

#define WRB(R)                                                  \
  { _Pragma("unroll") for (int i = 0; i < 4; ++i) {             \
      *(float4*)(&(R)[tg * 4 + i][eg * 8])     = acc0[i];       \
      *(float4*)(&(R)[tg * 4 + i][eg * 8 + 4]) = acc1[i]; } }
#define ADDB(R)                                                 \
  { _Pragma("unroll") for (int i = 0; i < 4; ++i) {             \
      const float4 t0 = *(const float4*)(&(R)[tg * 4 + i][eg * 8]);     \
      const float4 t1 = *(const float4*)(&(R)[tg * 4 + i][eg * 8 + 4]); \
      acc0[i].x += t0.x; acc0[i].y += t0.y;                     \
      acc0[i].z += t0.z; acc0[i].w += t0.w;                     \
      acc1[i].x += t1.x; acc1[i].y += t1.y;                     \
      acc1[i].z += t1.z; acc1[i].w += t1.w; } }

  // deterministic tree over 8 waves: pairwise (w, w+1) -> (w, w+2) -> (w, w+4)
  __syncthreads();
  if (w == 1) WRB(B0)
  if (w == 5) WRB(B1)
  __syncthreads();
  if (w == 0) ADDB(B0)
  if (w == 4) ADDB(B1)
  __syncthreads();
  if (w == 3) WRB(B0)
  if (w == 7) WRB(B1)
  __syncthreads();
  if (w == 2) ADDB(B0)
  if (w == 6) ADDB(B1)
  __syncthreads();
  if (w == 2) WRB(B0)
  if (w == 6) WRB(B1)
  __syncthreads();
  if (w == 0) ADDB(B0)
  if (w == 4) ADDB(B1)
  __syncthreads();
  if (w == 4) WRB(B0)
  __syncthreads();
  if (w == 0) {
    ADDB(B0)
#pragma unroll
    for (int i = 0; i < 4; ++i) {
      const int row = tg * 4 + i;
      const float qs = nq[0][row] + nq[1][row] + nq[2][row] + nq[3][row] +
                       nq[4][row] + nq[5][row] + nq[6][row] + nq[7][row];
      const float inv = 1.0f / fmaxf(sqrtf(qs), EPSV);
      float4 o0, o1;
      o0.x = acc0[i].x * inv; o0.y = acc0[i].y * inv;
      o0.z = acc0[i].z * inv; o0.w = acc0[i].w * inv;
      o1.x = acc1[i].x * inv; o1.y = acc1[i].y * inv;
      o1.z = acc1[i].z * inv; o1.w = acc1[i].w * inv;
      float* dp = dots + ((size_t)b * SS + s0 + row) * EE + eg * 8;
      *(float4*)(dp)     = o0;
      *(float4*)(dp + 4) = o1;
    }
  }
}

// ---- K2: window-3 + top-2 + renorm softmax (array-free, R7-verified) -------
#define T2UP(s, ei)                                            \
  if ((s) > v1) { v2 = v1; i2 = i1; v1 = (s); i1 = (ei); }     \
  else if ((s) > v2) { v2 = (s); i2 = (ei); }

__global__ __launch_bounds__(256) void router_top2(
    const float* __restrict__ dots, float* __restrict__ out) {
  const int gtid = blockIdx.x * 256 + threadIdx.x;  // 0..32767
  const int tok  = gtid >> 1;          // global token
  const int h    = gtid & 1;           // expert half (32 each)
  const int b    = tok >> 11;
  const int sl   = tok & (SS - 1);
  const int r0   = (sl >= 2) ? sl - 2 : 0;   // causal pad: replicate token 0
  const int r1   = (sl >= 1) ? sl - 1 : 0;

  const float* d0 = dots + ((size_t)b * SS + r0) * EE + h * 32;
  const float* d1 = dots + ((size_t)b * SS + r1) * EE + h * 32;
  const float* d2 = dots + ((size_t)b * SS + sl) * EE + h * 32;

  float v1 = -INFINITY, v2 = -INFINITY;
  int i1 = 0, i2 = 0;
#pragma unroll
  for (int qd = 0; qd < 8; ++qd) {
    const float4 a = *(const float4*)(d0 + qd * 4);
    const float4 c = *(const float4*)(d1 + qd * 4);
    const float4 e = *(const float4*)(d2 + qd * 4);
    const int e0 = h * 32 + qd * 4;
    float s;
    s = a.x + c.x + e.x; T2UP(s, e0 + 0)
    s = a.y + c.y + e.y; T2UP(s, e0 + 1)
    s = a.z + c.z + e.z; T2UP(s, e0 + 2)
    s = a.w + c.w + e.w; T2UP(s, e0 + 3)
  }

  {  // merge the two halves (partner lane = lane^1); tie -> lower index
    const float ov1 = __shfl_xor(v1, 1);
    const int   oi1 = __shfl_xor(i1, 1);
    const float ov2 = __shfl_xor(v2, 1);
    const int   oi2 = __shfl_xor(i2, 1);
    const bool o_beats = (ov1 > v1) || (ov1 == v1 && oi1 < i1);
    if (o_beats) {
      const bool v1_beats_o2 = (v1 > ov2) || (v1 == ov2 && i1 < oi2);
      v2 = v1_beats_o2 ? v1 : ov2;
      i2 = v1_beats_o2 ? i1 : oi2;
      v1 = ov1;
      i1 = oi1;
    } else {
      const bool o1_beats_v2 = (ov1 > v2) || (ov1 == v2 && oi1 < i2);
      if (o1_beats_v2) { v2 = ov1; i2 = oi1; }
    }
  }

  if (h == 0) {
    const float ex = expf((v2 - v1) * (1.0f / 3.0f));  // <= 1
    const float w1 = 1.0f / (1.0f + ex);
    const size_t o = (size_t)tok * 2;
    *(float2*)(out + o) = make_float2((float)i1, (float)i2);
    *(float2*)(out + (size_t)BB * SS * 2 + o) = make_float2(w1, ex * w1);
  }
}

extern "C" void kernel_launch(void* const* d_in, const int* in_sizes, int n_in,
                              void* d_out, int out_size, void* d_ws, size_t ws_size,
                              hipStream_t stream) {
  const float* x     = (const float*)d_in[0];
  const float* proto = (const float*)d_in[1];
  // d_in[2] = attn_mask: unused by the reference output path.
  float* out  = (float*)d_out;
  float* ptt  = (float*)d_ws;                          // 256 KiB ptt[d][e]
  float* dots = (float*)((char*)d_ws + (512 << 10));   // 4 MiB normalized dots

  repack_proto<<<dim3(256), dim3(256), 0, stream>>>(proto, ptt);
  router_dots<<<dim3(512), dim3(512), 0, stream>>>(x, ptt, dots);
  router_top2<<<dim3(128), dim3(256), 0, stream>>>(dots, out);
}

// Round 2
// 129.858 us; speedup vs baseline: 1.0562x; 1.0562x over previous
//
#include <hip/hip_runtime.h>
#include <math.h>

// ClownSelector R11: LDS-staged proto — kill the L1 return-bandwidth bound.
//
// R10 post-mortem: doubling waves/CU (8->16) left VALUBusy at 28% and dur
// flat. TLP-independent busy% => shared-pipe bound, not latency. The pipe:
// proto rotation loads 2x dwordx4 per k-step per wave = 2KB of L1 return
// traffic (8-way duplicated lane addresses) vs 64 SIMD-cyc of fmac. Total
// ~1.07 GB of TCP return for a 256KB array => ~27us of L1 occupancy vs
// ~14us FMA => predicted VALUBusy 28%. Matches R9 AND R10.
//
// R11: proto chunks (16k x 64e = 4KB) staged per-wave into double-buffered
// LDS with 4 coalesced dwordx4 per chunk (distinct addresses, 1KB each).
// k-loop reads proto via ds_read_b128: 8 distinct addrs, 8-way broadcast
// (free), 2-way distinct-addr bank alias (free per m136). Per-kstep vmem
// 2048B -> 384B. Proto LDS addressing folds to immediates (kk*256+{0,16}).
// B0/B1 epilogue buffers aliased into xt (dead after k-loop; __syncthreads
// separates) to keep LDS at 70.7KB -> 2 blocks/CU, 16 waves.
// Everything else is R10-verified and unchanged.

#define BB 8
#define SS 2048
#define DD 1024
#define EE 64
#define EPSV 1e-8f

#define FMA4(A, s, P) \
  A.x += (s) * (P).x; A.y += (s) * (P).y; A.z += (s) * (P).z; A.w += (s) * (P).w;

#define SUMSQ4(v) ((v).x * (v).x + (v).y * (v).y + (v).z * (v).z + (v).w * (v).w)

// ---- K0: proto[e][d] -> ptt[d][e] -----------------------------------------
__global__ __launch_bounds__(256) void repack_proto(
    const float* __restrict__ proto, float* __restrict__ ptt) {
  const int gid = blockIdx.x * 256 + threadIdx.x;  // 0..65535
  const int d = gid >> 6;
  const int e = gid & 63;
  ptt[gid] = proto[(size_t)e * DD + d];
}

// ---- K1: normalized per-row dots ------------------------------------------
__global__ __launch_bounds__(512, 2) void router_dots(
    const float* __restrict__ x, const float* __restrict__ ptt,
    float* __restrict__ dots) {
  __shared__ float xt[8][2][16][36];  // x chunks; ALIASED as B0/B1 in epilogue
  __shared__ float pt[8][2][16][64];  // proto chunks, per-wave double-buffered
  __shared__ float nq[8][32];         // per-wave per-token sumsq partials

  const int lane = threadIdx.x & 63;
  const int w    = __builtin_amdgcn_readfirstlane(threadIdx.x >> 6);  // 0..7
  const int b    = blockIdx.x >> 6;          // 64 blocks per batch
  const int s0   = (blockIdx.x & 63) * 32;   // 32 tokens per block

  const int toks = lane & 31;  // staging: token
  const int kh   = lane >> 5;  // staging: k-half (8 floats)
  const int eg   = lane & 7;   // tile: expert group (8 e)
  const int tg   = lane >> 3;  // tile: token group (4 t)

  const float* xb = x + ((size_t)b * SS + s0) * DD;
  const int kbase = w * 128;   // this wave's k-slice (128 wide)

  float4 acc0[4], acc1[4];
#pragma unroll
  for (int i = 0; i < 4; ++i) {
    acc0[i] = make_float4(0.f, 0.f, 0.f, 0.f);
    acc1[i] = make_float4(0.f, 0.f, 0.f, 0.f);
  }
  float q = 0.0f;

  // ---- prologue: stage chunk 0 (x + proto) into buf 0 ----
  {
    const float* xs = xb + (size_t)toks * DD + kbase + kh * 8;
    const float4 va = *(const float4*)(xs);
    const float4 vb = *(const float4*)(xs + 4);
    q += SUMSQ4(va) + SUMSQ4(vb);
    float* dstc = &xt[w][0][0][toks];
    dstc[(kh * 8 + 0) * 36] = va.x;
    dstc[(kh * 8 + 1) * 36] = va.y;
    dstc[(kh * 8 + 2) * 36] = va.z;
    dstc[(kh * 8 + 3) * 36] = va.w;
    dstc[(kh * 8 + 4) * 36] = vb.x;
    dstc[(kh * 8 + 5) * 36] = vb.y;
    dstc[(kh * 8 + 6) * 36] = vb.z;
    dstc[(kh * 8 + 7) * 36] = vb.w;

    const float* ps = ptt + (size_t)kbase * EE;
    const float4 q0 = *(const float4*)(ps + lane * 4);
    const float4 q1 = *(const float4*)(ps + 256 + lane * 4);
    const float4 q2 = *(const float4*)(ps + 512 + lane * 4);
    const float4 q3 = *(const float4*)(ps + 768 + lane * 4);
    float* pd = &pt[w][0][0][0] + lane * 4;
    *(float4*)(pd)       = q0;
    *(float4*)(pd + 256) = q1;
    *(float4*)(pd + 512) = q2;
    *(float4*)(pd + 768) = q3;
  }

  for (int c = 0; c < 8; ++c) {   // 8 chunks x 16 k = 128 k
    const int cur = c & 1;
    // ---- prefetch next chunk's x + proto (consumed after the k-loop) ----
    float4 na, nb, r0, r1, r2, r3;
    if (c + 1 < 8) {
      const float* xs = xb + (size_t)toks * DD + kbase + (c + 1) * 16 + kh * 8;
      na = *(const float4*)(xs);
      nb = *(const float4*)(xs + 4);
      const float* ps = ptt + (size_t)(kbase + (c + 1) * 16) * EE;
      r0 = *(const float4*)(ps + lane * 4);
      r1 = *(const float4*)(ps + 256 + lane * 4);
      r2 = *(const float4*)(ps + 512 + lane * 4);
      r3 = *(const float4*)(ps + 768 + lane * 4);
    }
    // ---- 16 k-steps: ds_read x-frag + ds_read proto + 32 fmac ----
    const float* xc = &xt[w][cur][0][tg * 4];
    const float* pc = &pt[w][cur][0][eg * 8];
#pragma unroll
    for (int kk = 0; kk < 16; ++kk) {
      const float4 xf = *(const float4*)(xc + kk * 36);
      const float4 p0 = *(const float4*)(pc + kk * 64);
      const float4 p1 = *(const float4*)(pc + kk * 64 + 4);
      FMA4(acc0[0], xf.x, p0) FMA4(acc1[0], xf.x, p1)
      FMA4(acc0[1], xf.y, p0) FMA4(acc1[1], xf.y, p1)
      FMA4(acc0[2], xf.z, p0) FMA4(acc1[2], xf.z, p1)
      FMA4(acc0[3], xf.w, p0) FMA4(acc1[3], xf.w, p1)
    }
    // ---- stage prefetched chunk into the other buffer ----
    if (c + 1 < 8) {
      q += SUMSQ4(na) + SUMSQ4(nb);
      float* dstc = &xt[w][cur ^ 1][0][toks];
      dstc[(kh * 8 + 0) * 36] = na.x;
      dstc[(kh * 8 + 1) * 36] = na.y;
      dstc[(kh * 8 + 2) * 36] = na.z;
      dstc[(kh * 8 + 3) * 36] = na.w;
      dstc[(kh * 8 + 4) * 36] = nb.x;
      dstc[(kh * 8 + 5) * 36] = nb.y;
      dstc[(kh * 8 + 6) * 36] = nb.z;
      dstc[(kh * 8 + 7) * 36] = nb.w;
      float* pd = &pt[w][cur ^ 1][0][0] + lane * 4;
      *(float4*)(pd)       = r0;
      *(float4*)(pd + 256) = r1;
      *(float4*)(pd + 512) = r2;
      *(float4*)(pd + 768) = r3;
    }
  }

  // sumsq: combine the two k-halves of each token; kh==0 lanes publish
  q += __shfl_xor(q, 32);
  if (kh == 0) nq[w][toks] = q;

  // epilogue reduction buffers alias the (now dead) xt region
  float (*B0)[68] = reinterpret_cast<float (*)[68]>(&xt[0][0][0][0]);
  float (*B1)[68] = reinterpret_cast<float (*)[68]>(&xt[0][0][0][0] + 32 * 68);

#define WRB(R)                                                  \
  { _Pragma("unroll") for (int i = 0; i < 4; ++i) {             \
      *(float4*)(&(R)[tg * 4 + i][eg * 8])     = acc0[i];       \
      *(float4*)(&(R)[tg * 4 + i][eg * 8 + 4]) = acc1[i]; } }
#define ADDB(R)                                                 \
  { _Pragma("unroll") for (int i = 0; i < 4; ++i) {             \
      const float4 t0 = *(const float4*)(&(R)[tg * 4 + i][eg * 8]);     \
      const float4 t1 = *(const float4*)(&(R)[tg * 4 + i][eg * 8 + 4]); \
      acc0[i].x += t0.x; acc0[i].y += t0.y;                     \
      acc0[i].z += t0.z; acc0[i].w += t0.w;                     \
      acc1[i].x += t1.x; acc1[i].y += t1.y;                     \
      acc1[i].z += t1.z; acc1[i].w += t1.w; } }

  // deterministic tree over 8 waves: pairwise (w, w+1) -> (w, w+2) -> (w, w+4)
  __syncthreads();
  if (w == 1) WRB(B0)
  if (w == 5) WRB(B1)
  __syncthreads();
  if (w == 0) ADDB(B0)
  if (w == 4) ADDB(B1)
  __syncthreads();
  if (w == 3) WRB(B0)
  if (w == 7) WRB(B1)
  __syncthreads();
  if (w == 2) ADDB(B0)
  if (w == 6) ADDB(B1)
  __syncthreads();
  if (w == 2) WRB(B0)
  if (w == 6) WRB(B1)
  __syncthreads();
  if (w == 0) ADDB(B0)
  if (w == 4) ADDB(B1)
  __syncthreads();
  if (w == 4) WRB(B0)
  __syncthreads();
  if (w == 0) {
    ADDB(B0)
#pragma unroll
    for (int i = 0; i < 4; ++i) {
      const int row = tg * 4 + i;
      const float qs = nq[0][row] + nq[1][row] + nq[2][row] + nq[3][row] +
                       nq[4][row] + nq[5][row] + nq[6][row] + nq[7][row];
      const float inv = 1.0f / fmaxf(sqrtf(qs), EPSV);
      float4 o0, o1;
      o0.x = acc0[i].x * inv; o0.y = acc0[i].y * inv;
      o0.z = acc0[i].z * inv; o0.w = acc0[i].w * inv;
      o1.x = acc1[i].x * inv; o1.y = acc1[i].y * inv;
      o1.z = acc1[i].z * inv; o1.w = acc1[i].w * inv;
      float* dp = dots + ((size_t)b * SS + s0 + row) * EE + eg * 8;
      *(float4*)(dp)     = o0;
      *(float4*)(dp + 4) = o1;
    }
  }
}

// ---- K2: window-3 + top-2 + renorm softmax (array-free, R7-verified) -------
#define T2UP(s, ei)                                            \
  if ((s) > v1) { v2 = v1; i2 = i1; v1 = (s); i1 = (ei); }     \
  else if ((s) > v2) { v2 = (s); i2 = (ei); }

__global__ __launch_bounds__(256) void router_top2(
    const float* __restrict__ dots, float* __restrict__ out) {
  const int gtid = blockIdx.x * 256 + threadIdx.x;  // 0..32767
  const int tok  = gtid >> 1;          // global token
  const int h    = gtid & 1;           // expert half (32 each)
  const int b    = tok >> 11;
  const int sl   = tok & (SS - 1);
  const int r0   = (sl >= 2) ? sl - 2 : 0;   // causal pad: replicate token 0
  const int r1   = (sl >= 1) ? sl - 1 : 0;

  const float* d0 = dots + ((size_t)b * SS + r0) * EE + h * 32;
  const float* d1 = dots + ((size_t)b * SS + r1) * EE + h * 32;
  const float* d2 = dots + ((size_t)b * SS + sl) * EE + h * 32;

  float v1 = -INFINITY, v2 = -INFINITY;
  int i1 = 0, i2 = 0;
#pragma unroll
  for (int qd = 0; qd < 8; ++qd) {
    const float4 a = *(const float4*)(d0 + qd * 4);
    const float4 c = *(const float4*)(d1 + qd * 4);
    const float4 e = *(const float4*)(d2 + qd * 4);
    const int e0 = h * 32 + qd * 4;
    float s;
    s = a.x + c.x + e.x; T2UP(s, e0 + 0)
    s = a.y + c.y + e.y; T2UP(s, e0 + 1)
    s = a.z + c.z + e.z; T2UP(s, e0 + 2)
    s = a.w + c.w + e.w; T2UP(s, e0 + 3)
  }

  {  // merge the two halves (partner lane = lane^1); tie -> lower index
    const float ov1 = __shfl_xor(v1, 1);
    const int   oi1 = __shfl_xor(i1, 1);
    const float ov2 = __shfl_xor(v2, 1);
    const int   oi2 = __shfl_xor(i2, 1);
    const bool o_beats = (ov1 > v1) || (ov1 == v1 && oi1 < i1);
    if (o_beats) {
      const bool v1_beats_o2 = (v1 > ov2) || (v1 == ov2 && i1 < oi2);
      v2 = v1_beats_o2 ? v1 : ov2;
      i2 = v1_beats_o2 ? i1 : oi2;
      v1 = ov1;
      i1 = oi1;
    } else {
      const bool o1_beats_v2 = (ov1 > v2) || (ov1 == v2 && oi1 < i2);
      if (o1_beats_v2) { v2 = ov1; i2 = oi1; }
    }
  }

  if (h == 0) {
    const float ex = expf((v2 - v1) * (1.0f / 3.0f));  // <= 1
    const float w1 = 1.0f / (1.0f + ex);
    const size_t o = (size_t)tok * 2;
    *(float2*)(out + o) = make_float2((float)i1, (float)i2);
    *(float2*)(out + (size_t)BB * SS * 2 + o) = make_float2(w1, ex * w1);
  }
}

extern "C" void kernel_launch(void* const* d_in, const int* in_sizes, int n_in,
                              void* d_out, int out_size, void* d_ws, size_t ws_size,
                              hipStream_t stream) {
  const float* x     = (const float*)d_in[0];
  const float* proto = (const float*)d_in[1];
  // d_in[2] = attn_mask: unused by the reference output path.
  float* out  = (float*)d_out;
  float* ptt  = (float*)d_ws;                          // 256 KiB ptt[d][e]
  float* dots = (float*)((char*)d_ws + (512 << 10));   // 4 MiB normalized dots

  repack_proto<<<dim3(256), dim3(256), 0, stream>>>(proto, ptt);
  router_dots<<<dim3(512), dim3(512), 0, stream>>>(x, ptt, dots);
  router_top2<<<dim3(128), dim3(256), 0, stream>>>(dots, out);
}